// Round 19
// baseline (155.957 us; speedup 1.0000x reference)
//
#include <hip/hip_runtime.h>
#include <math.h>

#define B_ 16
#define T_ 512
#define C_ 464
#define H_ 16
#define D_ 29
#define BT_ 8192
#define NQKV_P 1536   // QKV cols: [3][16 heads][32] (d padded 29->32, zero weight cols)
#define KP 480        // 464 padded to multiple of 32 (7 BK=64 bodies + 1 BK=32 tail)
#define C4 1856       // 4*C = 29*64 exactly
#define NPC 512

typedef __attribute__((ext_vector_type(8))) short short8;
typedef __attribute__((ext_vector_type(4))) float f32x4;
typedef __attribute__((ext_vector_type(16))) float f32x16;
typedef __attribute__((ext_vector_type(4))) unsigned short ushort4v;

static __device__ __forceinline__ unsigned short f2bf(float f) {
  union { float f; unsigned u; } v; v.f = f;
  unsigned r = v.u + 0x7FFFu + ((v.u >> 16) & 1u);
  return (unsigned short)(r >> 16);
}

static __device__ __forceinline__ void load_lds16(const void* g, void* l) {
  __builtin_amdgcn_global_load_lds((const __attribute__((address_space(1))) unsigned int*)g,
                                   (__attribute__((address_space(3))) unsigned int*)l,
                                   16, 0, 0);
}

#define CVTPK(dst, a, b) asm("v_cvt_pk_bf16_f32 %0, %1, %2" : "=v"(dst) : "v"(a), "v"(b))

// (1536*480 + 512*480 + 1856*480 + 512*1856) / 256
#define PREP_BLOCKS 11032

// ---------- merged: weight prep (blocks < PREP_BLOCKS) + rmsnorm1 (2 rows/block) ----------
__global__ void prep_norm(const float* __restrict__ wq, const float* __restrict__ wk,
                          const float* __restrict__ wv, const float* __restrict__ wproj,
                          const float* __restrict__ w1, const float* __restrict__ w2,
                          unsigned short* __restrict__ Wqkvt, unsigned short* __restrict__ Wprt,
                          unsigned short* __restrict__ W1t, unsigned short* __restrict__ W2t,
                          const float* __restrict__ X, const float* __restrict__ g1,
                          unsigned short* __restrict__ Y) {
  const int bid = blockIdx.x;
  if (bid < PREP_BLOCKS) {
    int idx = bid * 256 + threadIdx.x;
    const int S1 = NQKV_P * KP, S2 = NPC * KP, S3 = C4 * KP, S4 = NPC * C4;
    if (idx < S1) {
      int n = idx / KP, k = idx - n * KP;
      int which = n >> 9, h = (n >> 5) & 15, d = n & 31;
      float val = 0.f;
      if (d < D_ && k < C_) {
        const float* s = (which == 0) ? wq : (which == 1) ? wk : wv;
        val = s[((size_t)h * C_ + k) * D_ + d];
      }
      Wqkvt[idx] = f2bf(val);
      return;
    }
    idx -= S1;
    if (idx < S2) {
      int n = idx / KP, k = idx - n * KP;
      Wprt[idx] = f2bf((k < C_ && n < C_) ? wproj[(size_t)k * C_ + n] : 0.f);
      return;
    }
    idx -= S2;
    if (idx < S3) {
      int n = idx / KP, k = idx - n * KP;
      W1t[idx] = f2bf((k < C_) ? w1[(size_t)k * C4 + n] : 0.f);
      return;
    }
    idx -= S3;
    if (idx < S4) {
      int n = idx / C4, k = idx - n * C4;
      W2t[idx] = f2bf((n < C_) ? w2[(size_t)k * C_ + n] : 0.f);
    }
    return;
  }
  // rmsnorm: 2 rows per 256-thread block (2 waves per row); out cols 464..479 zeroed
  const int half = threadIdx.x >> 7;
  const int tid = threadIdx.x & 127;
  const int row = (bid - PREP_BLOCKS) * 2 + half;
  __shared__ float red[4];
  float4 v = make_float4(0.f, 0.f, 0.f, 0.f);
  float ss = 0.f;
  if (tid < C_ / 4) {
    v = ((const float4*)(X + (size_t)row * C_))[tid];
    ss = v.x * v.x + v.y * v.y + v.z * v.z + v.w * v.w;
  }
  #pragma unroll
  for (int off = 32; off > 0; off >>= 1) ss += __shfl_xor(ss, off);
  if ((threadIdx.x & 63) == 0) red[threadIdx.x >> 6] = ss;
  __syncthreads();
  float rs = rsqrtf((red[2 * half] + red[2 * half + 1]) * (1.f / C_) + 1e-5f);
  if (tid < C_ / 4) {
    float4 gg = ((const float4*)g1)[tid];
    ushort4v y;
    y.x = f2bf(v.x * rs * gg.x); y.y = f2bf(v.y * rs * gg.y);
    y.z = f2bf(v.z * rs * gg.z); y.w = f2bf(v.w * rs * gg.w);
    *(ushort4v*)(Y + (size_t)row * KP + tid * 4) = y;
  } else if (tid < KP / 4) {
    ushort4v z = {0, 0, 0, 0};
    *(ushort4v*)(Y + (size_t)row * KP + tid * 4) = z;
  }
}

// ---------------- rmsnorm: f32 [8192][464] -> bf16 [8192][480] ----------------
__launch_bounds__(128)
__global__ void rmsnorm_bf16(const float* __restrict__ X, const float* __restrict__ g,
                             unsigned short* __restrict__ Y) {
  const int row = blockIdx.x;
  const int tid = threadIdx.x;
  __shared__ float red[2];
  float4 v = make_float4(0.f, 0.f, 0.f, 0.f);
  float ss = 0.f;
  if (tid < C_ / 4) {
    v = ((const float4*)(X + (size_t)row * C_))[tid];
    ss = v.x * v.x + v.y * v.y + v.z * v.z + v.w * v.w;
  }
  #pragma unroll
  for (int off = 32; off > 0; off >>= 1) ss += __shfl_xor(ss, off);
  if ((tid & 63) == 0) red[tid >> 6] = ss;
  __syncthreads();
  float rs = rsqrtf((red[0] + red[1]) * (1.f / C_) + 1e-5f);
  if (tid < C_ / 4) {
    float4 gg = ((const float4*)g)[tid];
    ushort4v y;
    y.x = f2bf(v.x * rs * gg.x); y.y = f2bf(v.y * rs * gg.y);
    y.z = f2bf(v.z * rs * gg.z); y.w = f2bf(v.w * rs * gg.w);
    *(ushort4v*)(Y + (size_t)row * KP + tid * 4) = y;
  } else if (tid < KP / 4) {
    ushort4v z = {0, 0, 0, 0};
    *(ushort4v*)(Y + (size_t)row * KP + tid * 4) = z;
  }
}

// ---------------- bf16 MFMA GEMM: 128x64 tile, 4 waves (2x2), BK=64 bodies + tail -----
// r16-proven schedule: one wait+barrier pair to publish, one to free, per body.
// K compile-time: nfull BK=64 bodies + optional BK=32 tail (KP=480 -> 7+1; C4=1856 -> 29).
// vmcnt at body t = loads of batch t+1 in flight (6 full / 3 tail / 0 last), static.
// DEPTH=2, LDS 48KB -> 3 blocks/CU. Fully unrolled.
// EPI: 1 = res+bias->f32; 2 = silu->bf16; 3 = res->f32; 4 = QKV scatter (bit-ops only)
template<int EPI, int BM, int NT, int KT>
__launch_bounds__(256)
__global__ void gemm_mfma(const unsigned short* __restrict__ A,
                          const unsigned short* __restrict__ Bt,
                          float* __restrict__ Cf, unsigned short* __restrict__ Cb,
                          const float* __restrict__ res, const float* __restrict__ bias,
                          int N, int ldc,
                          unsigned short* __restrict__ Kb2, unsigned short* __restrict__ Vt2) {
  constexpr int MF = BM / 32;        // wave m-frags (wave rows = BM/2)
  constexpr int NF = NT / 32;        // wave n-frags
  constexpr int CA = BM / 64;        // A staging chunks per wave per 32-K half
  constexpr int CB = NT / 64;        // B staging chunks per wave per 32-K half
  constexpr int nfull = KT / 64;     // full 64-K bodies
  constexpr int tailb = (KT % 64) / 32;  // 0 or 1 trailing 32-K body
  constexpr int nb = nfull + tailb;
  __shared__ __align__(16) unsigned short As[2][2 * BM * 32];
  __shared__ __align__(16) unsigned short Bs[2][2 * NT * 32];
  const int tid = threadIdx.x;
  const int w = tid >> 6, lane = tid & 63;
  const int bm = blockIdx.x * BM, bn = blockIdx.y * NT;

  // staging (swizzle applied via per-lane source granule, linear LDS dest)
  const int q = lane >> 2;
  const int g = (lane & 3) ^ ((lane >> 3) & 3);
  const unsigned short* gA = A + (size_t)(bm + w * CA * 16 + q) * KT + g * 8;
  const unsigned short* gB = Bt + (size_t)(bn + w * CB * 16 + q) * KT + g * 8;

  // ds_read side
  const int fr = lane & 15;
  const int hi4 = lane >> 4;
  const int gp = hi4 ^ ((lane >> 1) & 3);
  const int wr = (w >> 1) * (BM / 2), wc = (w & 1) * (NT / 2);
  int aoff[MF], boff[NF];
  #pragma unroll
  for (int m = 0; m < MF; ++m) aoff[m] = (wr + m * 16 + fr) * 32 + gp * 8;
  #pragma unroll
  for (int n = 0; n < NF; ++n) boff[n] = (wc + n * 16 + fr) * 32 + gp * 8;

  f32x4 acc[MF][NF];
  #pragma unroll
  for (int m = 0; m < MF; ++m)
    #pragma unroll
    for (int n = 0; n < NF; ++n) acc[m][n] = (f32x4){0.f, 0.f, 0.f, 0.f};

#define STAGEH(BUF, HALF, KO) do { \
    _Pragma("unroll") for (int j = 0; j < CA; ++j) \
      load_lds16(gA + (size_t)(j * 16) * KT + (KO), &As[BUF][(HALF) * BM * 32 + (w * CA + j) * 512]); \
    _Pragma("unroll") for (int j = 0; j < CB; ++j) \
      load_lds16(gB + (size_t)(j * 16) * KT + (KO), &Bs[BUF][(HALF) * NT * 32 + (w * CB + j) * 512]); \
  } while (0)

#define STAGEB(BUF, BODY) do { \
    STAGEH(BUF, 0, (BODY) * 64); \
    if ((BODY) < nfull) STAGEH(BUF, 1, (BODY) * 64 + 32); \
  } while (0)

#define COMPUTE32(BUF, HALF) do { \
    short8 af[MF], bf[NF]; \
    _Pragma("unroll") for (int m = 0; m < MF; ++m) \
      af[m] = *(const short8*)(&As[BUF][(HALF) * BM * 32] + aoff[m]); \
    _Pragma("unroll") for (int n = 0; n < NF; ++n) \
      bf[n] = *(const short8*)(&Bs[BUF][(HALF) * NT * 32] + boff[n]); \
    _Pragma("unroll") for (int m = 0; m < MF; ++m) \
      _Pragma("unroll") for (int n = 0; n < NF; ++n) \
        acc[m][n] = __builtin_amdgcn_mfma_f32_16x16x32_bf16(af[m], bf[n], acc[m][n], 0, 0, 0); \
  } while (0)

  STAGEB(0, 0);
  STAGEB(1, 1);
  #pragma unroll
  for (int t = 0; t < nb; ++t) {
    if (t + 1 < nfull)   asm volatile("s_waitcnt vmcnt(6)" ::: "memory");  // next batch full
    else if (t + 1 < nb) asm volatile("s_waitcnt vmcnt(3)" ::: "memory");  // next batch = tail
    else                 asm volatile("s_waitcnt vmcnt(0)" ::: "memory");  // last body
    asm volatile("s_waitcnt lgkmcnt(0)" ::: "memory");
    __builtin_amdgcn_s_barrier();
    __builtin_amdgcn_sched_barrier(0);
    __builtin_amdgcn_s_setprio(1);
    COMPUTE32(t & 1, 0);
    if (t < nfull) COMPUTE32(t & 1, 1);
    __builtin_amdgcn_s_setprio(0);
    asm volatile("s_waitcnt lgkmcnt(0)" ::: "memory");                 // my reads retired
    __builtin_amdgcn_s_barrier();                                      // all waves done w/ buf
    __builtin_amdgcn_sched_barrier(0);
    if (t + 2 < nb) STAGEB(t & 1, t + 2);                              // refill freed buffer
  }
#undef STAGEH
#undef STAGEB
#undef COMPUTE32

  const int crow0 = bm + wr + hi4 * 4;
  const int ccol0 = bn + wc + fr;
  #pragma unroll
  for (int n = 0; n < NF; ++n) {
    const int col = ccol0 + n * 16;
    if (col >= N) continue;
    #pragma unroll
    for (int m = 0; m < MF; ++m) {
      #pragma unroll
      for (int r = 0; r < 4; ++r) {
        const int row = crow0 + m * 16 + r;
        const size_t o = (size_t)row * ldc + col;
        float v = acc[m][n][r];
        if (EPI == 1) Cf[o] = res[o] + v + bias[col];
        else if (EPI == 2) Cb[o] = f2bf(v / (1.f + __expf(-v)));
        else if (EPI == 3) Cf[o] = res[o] + v;
        else if (EPI == 4) {
          // padded layout: col = which*512 + hh*32 + d  (pure bit-ops; pads write 0)
          int which = col >> 9;
          int hh = (col >> 5) & 15;
          int d = col & 31;
          unsigned short bv = f2bf(v);
          if (which < 2) {
            unsigned short* dst = (which == 0) ? Cb : Kb2;
            int pg = (d >> 3) ^ ((row >> 1) & 3);
            dst[(size_t)row * 512 + hh * 32 + pg * 8 + (d & 7)] = bv;
          } else {
            int tt = row & 511;
            int pg = ((tt >> 3) & 7) ^ (d & 7);
            Vt2[((size_t)(((row >> 9) * 16 + hh) * 32 + d)) * 512 + (tt & ~63) + pg * 8 + (tt & 7)] = bv;
          }
        }
      }
    }
  }
}

// ---------------- MFMA flash attention ----------------
// block = 64 q rows of one (b,h); 2 waves (wave = 32-q strip); s-tiles of 64, dbuf.
// blk decode: bh = blk & 255, qt = 7 - (blk >> 8)  -> heavy blocks dispatch first.
// S^T = mfma32x32x16(K, Q^T): lane owns q = lane&31 -> per-lane online softmax.
// O^T = mfma(V^T, P^T): P^T frag built in-register (cvt_pk + permlane32_swap).
__launch_bounds__(128)
__global__ void attn_mfma(const unsigned short* __restrict__ Qb,
                          const unsigned short* __restrict__ Kb,
                          const unsigned short* __restrict__ Vt,
                          const float* __restrict__ pos_emb,
                          unsigned short* __restrict__ Ob) {
  __shared__ __align__(16) unsigned short Qs[2048];     // [64][32]
  __shared__ __align__(16) unsigned short Ks[2][2048];  // [64][32]
  __shared__ __align__(16) unsigned short Vs[2][2048];  // [32][64]
  __shared__ __align__(16) float pes[512];
  const int blk = blockIdx.x;
  const int bh = blk & 255, qt = 7 - (blk >> 8);
  const int b = bh >> 4, h = bh & 15;
  const int tid = threadIdx.x;
  const int w = tid >> 6, lane = tid & 63;
  const int l31 = lane & 31, hi = lane >> 5;
  const int qb = qt * 64;

  const char* gq = (const char*)Qb + ((size_t)(b * 512 + qb) * 512 + h * 32) * 2;
  const char* gk = (const char*)Kb + ((size_t)(b * 512) * 512 + h * 32) * 2;
  const char* gv = (const char*)Vt + ((size_t)(bh * 32) * 512) * 2;

  // prologue staging: Q (4KB), pe (2KB), tile0 K/V (4KB each); 128 thr, 2 calls each
  #pragma unroll
  for (int j = 0; j < 2; ++j) {
    const int ci = (w * 2 + j) * 64 + lane;
    load_lds16(gq + (size_t)(ci >> 2) * 1024 + (lane & 3) * 16, (char*)Qs + (w * 2 + j) * 1024);
    load_lds16(gk + (size_t)(ci >> 2) * 1024 + (lane & 3) * 16, (char*)Ks[0] + (w * 2 + j) * 1024);
    load_lds16(gv + (size_t)(ci >> 3) * 1024 + (lane & 7) * 16, (char*)Vs[0] + (w * 2 + j) * 1024);
  }
  load_lds16((const char*)pos_emb + h * 2048 + tid * 16, (char*)pes + w * 1024);
  __syncthreads();

  // hoist Q fragments (B-slot: lane holds Q[q=lane&31][d=hi*8+j+16kc])
  const int qrow = w * 32 + l31;
  short8 qf[2];
  #pragma unroll
  for (int kc = 0; kc < 2; ++kc) {
    int pg = (hi + 2 * kc) ^ ((qrow >> 1) & 3);
    qf[kc] = *(const short8*)(Qs + qrow * 32 + pg * 8);
  }

  const int t = qb + w * 32 + l31;
  const int nt = qt + 1;                     // tiles (both waves compute all of them)
  const float scale2 = 0.18569533817705186f * 1.4426950408889634f;  // 29^-.5 * log2e
  f32x16 oacc;
  #pragma unroll
  for (int r = 0; r < 16; ++r) oacc[r] = 0.f;
  float m_run = -1e30f, l_run = 0.f;

  for (int si = 0; si < nt; ++si) {
    const int c = si & 1;
    if (si + 1 < nt) {  // prefetch next tile into buf c^1
      const int sb = (si + 1) * 64;
      #pragma unroll
      for (int j = 0; j < 2; ++j) {
        const int ci = (w * 2 + j) * 64 + lane;
        load_lds16(gk + (size_t)(sb + (ci >> 2)) * 1024 + (lane & 3) * 16,
                   (char*)Ks[c ^ 1] + (w * 2 + j) * 1024);
        load_lds16(gv + (size_t)(ci >> 3) * 1024 + sb * 2 + (lane & 7) * 16,
                   (char*)Vs[c ^ 1] + (w * 2 + j) * 1024);
      }
    }
    {
      const int sbase = si * 64;
      f32x16 sc[2];
      #pragma unroll
      for (int sf = 0; sf < 2; ++sf) {
        int srow = 32 * sf + l31;
        f32x16 a;
        #pragma unroll
        for (int r = 0; r < 16; ++r) a[r] = 0.f;
        #pragma unroll
        for (int kc = 0; kc < 2; ++kc) {
          int pg = (hi + 2 * kc) ^ ((srow >> 1) & 3);
          short8 kf = *(const short8*)(&Ks[c][0] + srow * 32 + pg * 8);
          a = __builtin_amdgcn_mfma_f32_32x32x16_bf16(kf, qf[kc], a, 0, 0, 0);
        }
        sc[sf] = a;
      }
      const bool edge = (si == nt - 1);
      float mt = -1e30f;
      #pragma unroll
      for (int sf = 0; sf < 2; ++sf)
        #pragma unroll
        for (int r = 0; r < 16; ++r) {
          int s_abs = sbase + 32 * sf + ((r & 3) + 8 * (r >> 2)) + 4 * hi;
          int idx = t - s_abs;
          float v;
          if (edge) {
            float bias = pes[idx < 0 ? 0 : idx];
            v = (sc[sf][r] + bias) * scale2;
            if (idx < 0) v = -1e30f;
          } else {
            v = (sc[sf][r] + pes[idx]) * scale2;
          }
          sc[sf][r] = v;
          mt = fmaxf(mt, v);
        }
      mt = fmaxf(mt, __shfl_xor(mt, 32));
      if (mt > m_run + 11.5f) {   // defer-max (T13), exp2 space
        float corr = exp2f(m_run - mt);
        l_run *= corr;
        #pragma unroll
        for (int r = 0; r < 16; ++r) oacc[r] *= corr;
        m_run = mt;
      }
      float ls = 0.f;
      #pragma unroll
      for (int sf = 0; sf < 2; ++sf)
        #pragma unroll
        for (int r = 0; r < 16; ++r) {
          float p = exp2f(sc[sf][r] - m_run);
          sc[sf][r] = p;
          ls += p;
        }
      l_run += ls + __shfl_xor(ls, 32);
      // P^T fragments: per 16-s chunk kc: 4 bf16x2 words via cvt_pk + permlane32_swap.
      // permlane32_swap(vdst,vsrc): new vdst=[vdst_lo|vsrc_lo], new vsrc=[vdst_hi|vsrc_hi]
      unsigned pw[4][4];
      #pragma unroll
      for (int sf = 0; sf < 2; ++sf)
        #pragma unroll
        for (int kk = 0; kk < 2; ++kk) {
          const int kc = sf * 2 + kk;
          const int rb = kk * 8;
          unsigned pk01, pk23, pk45, pk67;
          CVTPK(pk01, sc[sf][rb + 0], sc[sf][rb + 1]);
          CVTPK(pk23, sc[sf][rb + 2], sc[sf][rb + 3]);
          CVTPK(pk45, sc[sf][rb + 4], sc[sf][rb + 5]);
          CVTPK(pk67, sc[sf][rb + 6], sc[sf][rb + 7]);
          asm volatile("v_permlane32_swap_b32 %0, %1" : "+v"(pk01), "+v"(pk45));
          asm volatile("v_permlane32_swap_b32 %0, %1" : "+v"(pk23), "+v"(pk67));
          pw[kc][0] = pk01; pw[kc][1] = pk23; pw[kc][2] = pk45; pw[kc][3] = pk67;
        }
      // PV: O^T += V^T · P^T
      #pragma unroll
      for (int kc = 0; kc < 4; ++kc) {
        int pg = (2 * kc + hi) ^ (l31 & 7);
        short8 vf = *(const short8*)(&Vs[c][0] + l31 * 64 + pg * 8);
        union { unsigned u[4]; short8 s8; } pu;
        pu.u[0] = pw[kc][0]; pu.u[1] = pw[kc][1]; pu.u[2] = pw[kc][2]; pu.u[3] = pw[kc][3];
        oacc = __builtin_amdgcn_mfma_f32_32x32x16_bf16(vf, pu.s8, oacc, 0, 0, 0);
      }
    }
    __syncthreads();
  }

  const float inv = 1.f / l_run;
  #pragma unroll
  for (int r = 0; r < 16; ++r) {
    int d = (r & 3) + 8 * (r >> 2) + 4 * hi;
    if (d < D_)
      Ob[(size_t)(b * 512 + t) * KP + h * D_ + d] = f2bf(oacc[r] * inv);
  }
  if (h == 15 && tid < 64) {  // zero ob pad cols 464..479 (NaN safety)
    char* p = (char*)(Ob + (size_t)(b * 512 + qb + tid) * KP + C_);
    *(uint4*)p = make_uint4(0, 0, 0, 0);
    *(uint4*)(p + 16) = make_uint4(0, 0, 0, 0);
  }
}

extern "C" void kernel_launch(void* const* d_in, const int* in_sizes, int n_in,
                              void* d_out, int out_size, void* d_ws, size_t ws_size,
                              hipStream_t stream) {
  const float* x       = (const float*)d_in[0];
  const float* wq      = (const float*)d_in[2];
  const float* wk      = (const float*)d_in[3];
  const float* wv      = (const float*)d_in[4];
  const float* pos_emb = (const float*)d_in[5];
  const float* w_proj  = (const float*)d_in[6];
  const float* b_proj  = (const float*)d_in[7];
  const float* g1      = (const float*)d_in[8];
  const float* g2      = (const float*)d_in[9];
  const float* w1      = (const float*)d_in[10];
  const float* w2      = (const float*)d_in[11];
  float* out = (float*)d_out;

  char* cur = (char*)d_ws;
  auto alloc = [&](size_t bytes) { char* p = cur; cur += (bytes + 255) & ~(size_t)255; return p; };
  unsigned short* Wqkvt = (unsigned short*)alloc((size_t)NQKV_P * KP * 2);
  unsigned short* Wprt  = (unsigned short*)alloc((size_t)NPC * KP * 2);
  unsigned short* W1t   = (unsigned short*)alloc((size_t)C4 * KP * 2);
  unsigned short* W2t   = (unsigned short*)alloc((size_t)NPC * C4 * 2);
  unsigned short* h1b   = (unsigned short*)alloc((size_t)BT_ * KP * 2);
  unsigned short* ob    = (unsigned short*)alloc((size_t)BT_ * KP * 2);
  unsigned short* ffb   = (unsigned short*)alloc((size_t)BT_ * C4 * 2);
  unsigned short* Qbuf  = (unsigned short*)alloc((size_t)BT_ * 512 * 2);
  unsigned short* Kbuf  = (unsigned short*)alloc((size_t)BT_ * 512 * 2);
  unsigned short* Vtb   = (unsigned short*)alloc((size_t)BT_ * 512 * 2);

  prep_norm<<<PREP_BLOCKS + BT_ / 2, 256, 0, stream>>>(
      wq, wk, wv, w_proj, w1, w2, Wqkvt, Wprt, W1t, W2t, x, g1, h1b);

  gemm_mfma<4, 128, 64, KP><<<dim3(BT_ / 128, NQKV_P / 64), 256, 0, stream>>>(
      h1b, Wqkvt, nullptr, Qbuf, nullptr, nullptr, NQKV_P, 0, Kbuf, Vtb);
  attn_mfma<<<B_ * H_ * 8, 128, 0, stream>>>(Qbuf, Kbuf, Vtb, pos_emb, ob);
  gemm_mfma<1, 128, 64, KP><<<dim3(BT_ / 128, NPC / 64), 256, 0, stream>>>(
      ob, Wprt, out, nullptr, x, b_proj, C_, C_, nullptr, nullptr);
  rmsnorm_bf16<<<BT_, 128, 0, stream>>>(out, g2, h1b);
  gemm_mfma<2, 128, 64, KP><<<dim3(BT_ / 128, C4 / 64), 256, 0, stream>>>(
      h1b, W1t, nullptr, ffb, nullptr, nullptr, C4, C4, nullptr, nullptr);
  gemm_mfma<3, 128, 64, C4><<<dim3(BT_ / 128, NPC / 64), 256, 0, stream>>>(
      ffb, W2t, out, nullptr, out, nullptr, C_, C_, nullptr, nullptr);
}

// Round 20
// 147.804 us; speedup vs baseline: 1.0552x; 1.0552x over previous
//
#include <hip/hip_runtime.h>
#include <math.h>

#define B_ 16
#define T_ 512
#define C_ 464
#define H_ 16
#define D_ 29
#define BT_ 8192
#define NQKV_P 1536   // QKV cols: [3][16 heads][32] (d padded 29->32, zero weight cols)
#define KP 512        // 464 padded to multiple of 64 (BK=64 bodies)
#define C4 1856       // 4*C = 29*64 exactly
#define NPC 512

typedef __attribute__((ext_vector_type(8))) short short8;
typedef __attribute__((ext_vector_type(4))) float f32x4;
typedef __attribute__((ext_vector_type(16))) float f32x16;
typedef __attribute__((ext_vector_type(4))) unsigned short ushort4v;

static __device__ __forceinline__ unsigned short f2bf(float f) {
  union { float f; unsigned u; } v; v.f = f;
  unsigned r = v.u + 0x7FFFu + ((v.u >> 16) & 1u);
  return (unsigned short)(r >> 16);
}

static __device__ __forceinline__ void load_lds16(const void* g, void* l) {
  __builtin_amdgcn_global_load_lds((const __attribute__((address_space(1))) unsigned int*)g,
                                   (__attribute__((address_space(3))) unsigned int*)l,
                                   16, 0, 0);
}

#define CVTPK(dst, a, b) asm("v_cvt_pk_bf16_f32 %0, %1, %2" : "=v"(dst) : "v"(a), "v"(b))

// (1536*512 + 512*512 + 1856*512 + 512*1856) / 256
#define PREP_BLOCKS 11520

// ---------- merged: weight prep (blocks < PREP_BLOCKS) + rmsnorm1 (2 rows/block) ----------
__global__ void prep_norm(const float* __restrict__ wq, const float* __restrict__ wk,
                          const float* __restrict__ wv, const float* __restrict__ wproj,
                          const float* __restrict__ w1, const float* __restrict__ w2,
                          unsigned short* __restrict__ Wqkvt, unsigned short* __restrict__ Wprt,
                          unsigned short* __restrict__ W1t, unsigned short* __restrict__ W2t,
                          const float* __restrict__ X, const float* __restrict__ g1,
                          unsigned short* __restrict__ Y) {
  const int bid = blockIdx.x;
  if (bid < PREP_BLOCKS) {
    int idx = bid * 256 + threadIdx.x;
    const int S1 = NQKV_P * KP, S2 = NPC * KP, S3 = C4 * KP, S4 = NPC * C4;
    if (idx < S1) {
      int n = idx >> 9, k = idx & 511;
      int which = n >> 9, h = (n >> 5) & 15, d = n & 31;
      float val = 0.f;
      if (d < D_ && k < C_) {
        const float* s = (which == 0) ? wq : (which == 1) ? wk : wv;
        val = s[((size_t)h * C_ + k) * D_ + d];
      }
      Wqkvt[idx] = f2bf(val);
      return;
    }
    idx -= S1;
    if (idx < S2) {
      int n = idx >> 9, k = idx & 511;
      Wprt[idx] = f2bf((k < C_ && n < C_) ? wproj[(size_t)k * C_ + n] : 0.f);
      return;
    }
    idx -= S2;
    if (idx < S3) {
      int n = idx >> 9, k = idx & 511;
      W1t[idx] = f2bf((k < C_) ? w1[(size_t)k * C4 + n] : 0.f);
      return;
    }
    idx -= S3;
    if (idx < S4) {
      int n = idx / C4, k = idx - n * C4;
      W2t[idx] = f2bf((n < C_) ? w2[(size_t)k * C_ + n] : 0.f);
    }
    return;
  }
  // rmsnorm: 2 rows per 256-thread block (2 waves per row); out cols 464..511 zeroed
  const int half = threadIdx.x >> 7;
  const int tid = threadIdx.x & 127;
  const int row = (bid - PREP_BLOCKS) * 2 + half;
  __shared__ float red[4];
  float4 v = make_float4(0.f, 0.f, 0.f, 0.f);
  float ss = 0.f;
  if (tid < C_ / 4) {
    v = ((const float4*)(X + (size_t)row * C_))[tid];
    ss = v.x * v.x + v.y * v.y + v.z * v.z + v.w * v.w;
  }
  #pragma unroll
  for (int off = 32; off > 0; off >>= 1) ss += __shfl_xor(ss, off);
  if ((threadIdx.x & 63) == 0) red[threadIdx.x >> 6] = ss;
  __syncthreads();
  float rs = rsqrtf((red[2 * half] + red[2 * half + 1]) * (1.f / C_) + 1e-5f);
  if (tid < C_ / 4) {
    float4 gg = ((const float4*)g1)[tid];
    ushort4v y;
    y.x = f2bf(v.x * rs * gg.x); y.y = f2bf(v.y * rs * gg.y);
    y.z = f2bf(v.z * rs * gg.z); y.w = f2bf(v.w * rs * gg.w);
    *(ushort4v*)(Y + (size_t)row * KP + tid * 4) = y;
  } else {
    ushort4v z = {0, 0, 0, 0};
    *(ushort4v*)(Y + (size_t)row * KP + tid * 4) = z;
  }
}

// ---------------- rmsnorm: f32 [8192][464] -> bf16 [8192][512] ----------------
__launch_bounds__(128)
__global__ void rmsnorm_bf16(const float* __restrict__ X, const float* __restrict__ g,
                             unsigned short* __restrict__ Y) {
  const int row = blockIdx.x;
  const int tid = threadIdx.x;
  __shared__ float red[2];
  float4 v = make_float4(0.f, 0.f, 0.f, 0.f);
  float ss = 0.f;
  if (tid < C_ / 4) {
    v = ((const float4*)(X + (size_t)row * C_))[tid];
    ss = v.x * v.x + v.y * v.y + v.z * v.z + v.w * v.w;
  }
  #pragma unroll
  for (int off = 32; off > 0; off >>= 1) ss += __shfl_xor(ss, off);
  if ((tid & 63) == 0) red[tid >> 6] = ss;
  __syncthreads();
  float rs = rsqrtf((red[0] + red[1]) * (1.f / C_) + 1e-5f);
  if (tid < C_ / 4) {
    float4 gg = ((const float4*)g)[tid];
    ushort4v y;
    y.x = f2bf(v.x * rs * gg.x); y.y = f2bf(v.y * rs * gg.y);
    y.z = f2bf(v.z * rs * gg.z); y.w = f2bf(v.w * rs * gg.w);
    *(ushort4v*)(Y + (size_t)row * KP + tid * 4) = y;
  } else {
    ushort4v z = {0, 0, 0, 0};
    *(ushort4v*)(Y + (size_t)row * KP + tid * 4) = z;
  }
}

// ---------------- bf16 MFMA GEMM: 128x64 tile, 4 waves (2x2), BK=64 bodies ------------
// r16-proven schedule: one wait(vmcnt 6)+barrier per 64-K body; compute both 32-K
// halves; lgkm(0)+barrier; stage batch t+2 into freed buffer. DEPTH=2, LDS 48KB ->
// 3 blocks/CU. K compile-time, fully unrolled. s_setprio around MFMA cluster (T5).
// EPI: 1 = res+bias->f32; 2 = silu->bf16; 3 = res->f32; 4 = QKV scatter (bit-ops only)
template<int EPI, int BM, int NT, int KT>
__launch_bounds__(256)
__global__ void gemm_mfma(const unsigned short* __restrict__ A,
                          const unsigned short* __restrict__ Bt,
                          float* __restrict__ Cf, unsigned short* __restrict__ Cb,
                          const float* __restrict__ res, const float* __restrict__ bias,
                          int N, int ldc,
                          unsigned short* __restrict__ Kb2, unsigned short* __restrict__ Vt2) {
  constexpr int MF = BM / 32;        // wave m-frags (wave rows = BM/2)
  constexpr int NF = NT / 32;        // wave n-frags
  constexpr int CA = BM / 64;        // A staging chunks per wave per 32-K half
  constexpr int CB = NT / 64;        // B staging chunks per wave per 32-K half
  constexpr int nt = KT >> 6;        // 64-K bodies
  __shared__ __align__(16) unsigned short As[2][2 * BM * 32];
  __shared__ __align__(16) unsigned short Bs[2][2 * NT * 32];
  const int tid = threadIdx.x;
  const int w = tid >> 6, lane = tid & 63;
  const int bm = blockIdx.x * BM, bn = blockIdx.y * NT;

  // staging (swizzle applied via per-lane source granule, linear LDS dest)
  const int q = lane >> 2;
  const int g = (lane & 3) ^ ((lane >> 3) & 3);
  const unsigned short* gA = A + (size_t)(bm + w * CA * 16 + q) * KT + g * 8;
  const unsigned short* gB = Bt + (size_t)(bn + w * CB * 16 + q) * KT + g * 8;

  // ds_read side
  const int fr = lane & 15;
  const int hi4 = lane >> 4;
  const int gp = hi4 ^ ((lane >> 1) & 3);
  const int wr = (w >> 1) * (BM / 2), wc = (w & 1) * (NT / 2);
  int aoff[MF], boff[NF];
  #pragma unroll
  for (int m = 0; m < MF; ++m) aoff[m] = (wr + m * 16 + fr) * 32 + gp * 8;
  #pragma unroll
  for (int n = 0; n < NF; ++n) boff[n] = (wc + n * 16 + fr) * 32 + gp * 8;

  f32x4 acc[MF][NF];
  #pragma unroll
  for (int m = 0; m < MF; ++m)
    #pragma unroll
    for (int n = 0; n < NF; ++n) acc[m][n] = (f32x4){0.f, 0.f, 0.f, 0.f};

#define STAGE64(BUF, KO) do { \
    _Pragma("unroll") for (int j = 0; j < CA; ++j) \
      load_lds16(gA + (size_t)(j * 16) * KT + (KO), &As[BUF][(w * CA + j) * 512]); \
    _Pragma("unroll") for (int j = 0; j < CA; ++j) \
      load_lds16(gA + (size_t)(j * 16) * KT + (KO) + 32, &As[BUF][BM * 32 + (w * CA + j) * 512]); \
    _Pragma("unroll") for (int j = 0; j < CB; ++j) \
      load_lds16(gB + (size_t)(j * 16) * KT + (KO), &Bs[BUF][(w * CB + j) * 512]); \
    _Pragma("unroll") for (int j = 0; j < CB; ++j) \
      load_lds16(gB + (size_t)(j * 16) * KT + (KO) + 32, &Bs[BUF][NT * 32 + (w * CB + j) * 512]); \
  } while (0)

#define COMPUTE32(BUF, HALF) do { \
    short8 af[MF], bf[NF]; \
    _Pragma("unroll") for (int m = 0; m < MF; ++m) \
      af[m] = *(const short8*)(&As[BUF][(HALF) * BM * 32] + aoff[m]); \
    _Pragma("unroll") for (int n = 0; n < NF; ++n) \
      bf[n] = *(const short8*)(&Bs[BUF][(HALF) * NT * 32] + boff[n]); \
    _Pragma("unroll") for (int m = 0; m < MF; ++m) \
      _Pragma("unroll") for (int n = 0; n < NF; ++n) \
        acc[m][n] = __builtin_amdgcn_mfma_f32_16x16x32_bf16(af[m], bf[n], acc[m][n], 0, 0, 0); \
  } while (0)

  STAGE64(0, 0);
  STAGE64(1, 64);
  #pragma unroll
  for (int t = 0; t < nt; ++t) {
    if (t + 1 < nt) asm volatile("s_waitcnt vmcnt(6)" ::: "memory");   // batch t done; t+1 flies
    else            asm volatile("s_waitcnt vmcnt(0)" ::: "memory");
    asm volatile("s_waitcnt lgkmcnt(0)" ::: "memory");
    __builtin_amdgcn_s_barrier();
    __builtin_amdgcn_sched_barrier(0);
    __builtin_amdgcn_s_setprio(1);
    COMPUTE32(t & 1, 0);
    COMPUTE32(t & 1, 1);
    __builtin_amdgcn_s_setprio(0);
    asm volatile("s_waitcnt lgkmcnt(0)" ::: "memory");                 // my reads retired
    __builtin_amdgcn_s_barrier();                                      // all waves done w/ buf
    __builtin_amdgcn_sched_barrier(0);
    if (t + 2 < nt) STAGE64(t & 1, (t + 2) * 64);                      // refill freed buffer
  }
#undef STAGE64
#undef COMPUTE32

  const int crow0 = bm + wr + hi4 * 4;
  const int ccol0 = bn + wc + fr;
  #pragma unroll
  for (int n = 0; n < NF; ++n) {
    const int col = ccol0 + n * 16;
    if (col >= N) continue;
    #pragma unroll
    for (int m = 0; m < MF; ++m) {
      #pragma unroll
      for (int r = 0; r < 4; ++r) {
        const int row = crow0 + m * 16 + r;
        const size_t o = (size_t)row * ldc + col;
        float v = acc[m][n][r];
        if (EPI == 1) Cf[o] = res[o] + v + bias[col];
        else if (EPI == 2) Cb[o] = f2bf(v / (1.f + __expf(-v)));
        else if (EPI == 3) Cf[o] = res[o] + v;
        else if (EPI == 4) {
          // padded layout: col = which*512 + hh*32 + d  (pure bit-ops; pads write 0)
          int which = col >> 9;
          int hh = (col >> 5) & 15;
          int d = col & 31;
          unsigned short bv = f2bf(v);
          if (which < 2) {
            unsigned short* dst = (which == 0) ? Cb : Kb2;
            int pg = (d >> 3) ^ ((row >> 1) & 3);
            dst[(size_t)row * 512 + hh * 32 + pg * 8 + (d & 7)] = bv;
          } else {
            int tt = row & 511;
            int pg = ((tt >> 3) & 7) ^ (d & 7);
            Vt2[((size_t)(((row >> 9) * 16 + hh) * 32 + d)) * 512 + (tt & ~63) + pg * 8 + (tt & 7)] = bv;
          }
        }
      }
    }
  }
}

// ---------------- MFMA flash attention ----------------
// block = 64 q rows of one (b,h); 2 waves (wave = 32-q strip); s-tiles of 64, dbuf.
// blk decode: bh = blk & 255, qt = 7 - (blk >> 8)  -> heavy blocks dispatch first.
// S^T = mfma32x32x16(K, Q^T): lane owns q = lane&31 -> per-lane online softmax.
// O^T = mfma(V^T, P^T): P^T frag built in-register (cvt_pk + permlane32_swap).
__launch_bounds__(128)
__global__ void attn_mfma(const unsigned short* __restrict__ Qb,
                          const unsigned short* __restrict__ Kb,
                          const unsigned short* __restrict__ Vt,
                          const float* __restrict__ pos_emb,
                          unsigned short* __restrict__ Ob) {
  __shared__ __align__(16) unsigned short Qs[2048];     // [64][32]
  __shared__ __align__(16) unsigned short Ks[2][2048];  // [64][32]
  __shared__ __align__(16) unsigned short Vs[2][2048];  // [32][64]
  __shared__ __align__(16) float pes[512];
  const int blk = blockIdx.x;
  const int bh = blk & 255, qt = 7 - (blk >> 8);
  const int b = bh >> 4, h = bh & 15;
  const int tid = threadIdx.x;
  const int w = tid >> 6, lane = tid & 63;
  const int l31 = lane & 31, hi = lane >> 5;
  const int qb = qt * 64;

  const char* gq = (const char*)Qb + ((size_t)(b * 512 + qb) * 512 + h * 32) * 2;
  const char* gk = (const char*)Kb + ((size_t)(b * 512) * 512 + h * 32) * 2;
  const char* gv = (const char*)Vt + ((size_t)(bh * 32) * 512) * 2;

  // prologue staging: Q (4KB), pe (2KB), tile0 K/V (4KB each); 128 thr, 2 calls each
  #pragma unroll
  for (int j = 0; j < 2; ++j) {
    const int ci = (w * 2 + j) * 64 + lane;
    load_lds16(gq + (size_t)(ci >> 2) * 1024 + (lane & 3) * 16, (char*)Qs + (w * 2 + j) * 1024);
    load_lds16(gk + (size_t)(ci >> 2) * 1024 + (lane & 3) * 16, (char*)Ks[0] + (w * 2 + j) * 1024);
    load_lds16(gv + (size_t)(ci >> 3) * 1024 + (lane & 7) * 16, (char*)Vs[0] + (w * 2 + j) * 1024);
  }
  load_lds16((const char*)pos_emb + h * 2048 + tid * 16, (char*)pes + w * 1024);
  __syncthreads();

  // hoist Q fragments (B-slot: lane holds Q[q=lane&31][d=hi*8+j+16kc])
  const int qrow = w * 32 + l31;
  short8 qf[2];
  #pragma unroll
  for (int kc = 0; kc < 2; ++kc) {
    int pg = (hi + 2 * kc) ^ ((qrow >> 1) & 3);
    qf[kc] = *(const short8*)(Qs + qrow * 32 + pg * 8);
  }

  const int t = qb + w * 32 + l31;
  const int nt = qt + 1;                     // tiles (both waves compute all of them)
  const float scale2 = 0.18569533817705186f * 1.4426950408889634f;  // 29^-.5 * log2e
  f32x16 oacc;
  #pragma unroll
  for (int r = 0; r < 16; ++r) oacc[r] = 0.f;
  float m_run = -1e30f, l_run = 0.f;

  for (int si = 0; si < nt; ++si) {
    const int c = si & 1;
    if (si + 1 < nt) {  // prefetch next tile into buf c^1
      const int sb = (si + 1) * 64;
      #pragma unroll
      for (int j = 0; j < 2; ++j) {
        const int ci = (w * 2 + j) * 64 + lane;
        load_lds16(gk + (size_t)(sb + (ci >> 2)) * 1024 + (lane & 3) * 16,
                   (char*)Ks[c ^ 1] + (w * 2 + j) * 1024);
        load_lds16(gv + (size_t)(ci >> 3) * 1024 + sb * 2 + (lane & 7) * 16,
                   (char*)Vs[c ^ 1] + (w * 2 + j) * 1024);
      }
    }
    {
      const int sbase = si * 64;
      f32x16 sc[2];
      #pragma unroll
      for (int sf = 0; sf < 2; ++sf) {
        int srow = 32 * sf + l31;
        f32x16 a;
        #pragma unroll
        for (int r = 0; r < 16; ++r) a[r] = 0.f;
        #pragma unroll
        for (int kc = 0; kc < 2; ++kc) {
          int pg = (hi + 2 * kc) ^ ((srow >> 1) & 3);
          short8 kf = *(const short8*)(&Ks[c][0] + srow * 32 + pg * 8);
          a = __builtin_amdgcn_mfma_f32_32x32x16_bf16(kf, qf[kc], a, 0, 0, 0);
        }
        sc[sf] = a;
      }
      const bool edge = (si == nt - 1);
      float mt = -1e30f;
      #pragma unroll
      for (int sf = 0; sf < 2; ++sf)
        #pragma unroll
        for (int r = 0; r < 16; ++r) {
          int s_abs = sbase + 32 * sf + ((r & 3) + 8 * (r >> 2)) + 4 * hi;
          int idx = t - s_abs;
          float v;
          if (edge) {
            float bias = pes[idx < 0 ? 0 : idx];
            v = (sc[sf][r] + bias) * scale2;
            if (idx < 0) v = -1e30f;
          } else {
            v = (sc[sf][r] + pes[idx]) * scale2;
          }
          sc[sf][r] = v;
          mt = fmaxf(mt, v);
        }
      mt = fmaxf(mt, __shfl_xor(mt, 32));
      if (mt > m_run + 11.5f) {   // defer-max (T13), exp2 space
        float corr = exp2f(m_run - mt);
        l_run *= corr;
        #pragma unroll
        for (int r = 0; r < 16; ++r) oacc[r] *= corr;
        m_run = mt;
      }
      float ls = 0.f;
      #pragma unroll
      for (int sf = 0; sf < 2; ++sf)
        #pragma unroll
        for (int r = 0; r < 16; ++r) {
          float p = exp2f(sc[sf][r] - m_run);
          sc[sf][r] = p;
          ls += p;
        }
      l_run += ls + __shfl_xor(ls, 32);
      // P^T fragments: per 16-s chunk kc: 4 bf16x2 words via cvt_pk + permlane32_swap.
      // permlane32_swap(vdst,vsrc): new vdst=[vdst_lo|vsrc_lo], new vsrc=[vdst_hi|vsrc_hi]
      unsigned pw[4][4];
      #pragma unroll
      for (int sf = 0; sf < 2; ++sf)
        #pragma unroll
        for (int kk = 0; kk < 2; ++kk) {
          const int kc = sf * 2 + kk;
          const int rb = kk * 8;
          unsigned pk01, pk23, pk45, pk67;
          CVTPK(pk01, sc[sf][rb + 0], sc[sf][rb + 1]);
          CVTPK(pk23, sc[sf][rb + 2], sc[sf][rb + 3]);
          CVTPK(pk45, sc[sf][rb + 4], sc[sf][rb + 5]);
          CVTPK(pk67, sc[sf][rb + 6], sc[sf][rb + 7]);
          asm volatile("v_permlane32_swap_b32 %0, %1" : "+v"(pk01), "+v"(pk45));
          asm volatile("v_permlane32_swap_b32 %0, %1" : "+v"(pk23), "+v"(pk67));
          pw[kc][0] = pk01; pw[kc][1] = pk23; pw[kc][2] = pk45; pw[kc][3] = pk67;
        }
      // PV: O^T += V^T · P^T
      #pragma unroll
      for (int kc = 0; kc < 4; ++kc) {
        int pg = (2 * kc + hi) ^ (l31 & 7);
        short8 vf = *(const short8*)(&Vs[c][0] + l31 * 64 + pg * 8);
        union { unsigned u[4]; short8 s8; } pu;
        pu.u[0] = pw[kc][0]; pu.u[1] = pw[kc][1]; pu.u[2] = pw[kc][2]; pu.u[3] = pw[kc][3];
        oacc = __builtin_amdgcn_mfma_f32_32x32x16_bf16(vf, pu.s8, oacc, 0, 0, 0);
      }
    }
    __syncthreads();
  }

  const float inv = 1.f / l_run;
  #pragma unroll
  for (int r = 0; r < 16; ++r) {
    int d = (r & 3) + 8 * (r >> 2) + 4 * hi;
    if (d < D_)
      Ob[(size_t)(b * 512 + t) * KP + h * D_ + d] = f2bf(oacc[r] * inv);
  }
  if (h == 15 && tid < 64) {  // zero ob pad cols 464..511 (NaN safety)
    char* p = (char*)(Ob + (size_t)(b * 512 + qb + tid) * KP + C_);
    *(uint4*)p = make_uint4(0, 0, 0, 0);
    *(uint4*)(p + 16) = make_uint4(0, 0, 0, 0);
    *(uint4*)(p + 32) = make_uint4(0, 0, 0, 0);
    *(uint4*)(p + 48) = make_uint4(0, 0, 0, 0);
    *(uint4*)(p + 64) = make_uint4(0, 0, 0, 0);
    *(uint4*)(p + 80) = make_uint4(0, 0, 0, 0);
  }
}

extern "C" void kernel_launch(void* const* d_in, const int* in_sizes, int n_in,
                              void* d_out, int out_size, void* d_ws, size_t ws_size,
                              hipStream_t stream) {
  const float* x       = (const float*)d_in[0];
  const float* wq      = (const float*)d_in[2];
  const float* wk      = (const float*)d_in[3];
  const float* wv      = (const float*)d_in[4];
  const float* pos_emb = (const float*)d_in[5];
  const float* w_proj  = (const float*)d_in[6];
  const float* b_proj  = (const float*)d_in[7];
  const float* g1      = (const float*)d_in[8];
  const float* g2      = (const float*)d_in[9];
  const float* w1      = (const float*)d_in[10];
  const float* w2      = (const float*)d_in[11];
  float* out = (float*)d_out;

  char* cur = (char*)d_ws;
  auto alloc = [&](size_t bytes) { char* p = cur; cur += (bytes + 255) & ~(size_t)255; return p; };
  unsigned short* Wqkvt = (unsigned short*)alloc((size_t)NQKV_P * KP * 2);
  unsigned short* Wprt  = (unsigned short*)alloc((size_t)NPC * KP * 2);
  unsigned short* W1t   = (unsigned short*)alloc((size_t)C4 * KP * 2);
  unsigned short* W2t   = (unsigned short*)alloc((size_t)NPC * C4 * 2);
  unsigned short* h1b   = (unsigned short*)alloc((size_t)BT_ * KP * 2);
  unsigned short* ob    = (unsigned short*)alloc((size_t)BT_ * KP * 2);
  unsigned short* ffb   = (unsigned short*)alloc((size_t)BT_ * C4 * 2);
  unsigned short* Qbuf  = (unsigned short*)alloc((size_t)BT_ * 512 * 2);
  unsigned short* Kbuf  = (unsigned short*)alloc((size_t)BT_ * 512 * 2);
  unsigned short* Vtb   = (unsigned short*)alloc((size_t)BT_ * 512 * 2);

  prep_norm<<<PREP_BLOCKS + BT_ / 2, 256, 0, stream>>>(
      wq, wk, wv, w_proj, w1, w2, Wqkvt, Wprt, W1t, W2t, x, g1, h1b);

  gemm_mfma<4, 128, 64, KP><<<dim3(BT_ / 128, NQKV_P / 64), 256, 0, stream>>>(
      h1b, Wqkvt, nullptr, Qbuf, nullptr, nullptr, NQKV_P, 0, Kbuf, Vtb);
  attn_mfma<<<B_ * H_ * 8, 128, 0, stream>>>(Qbuf, Kbuf, Vtb, pos_emb, ob);
  gemm_mfma<1, 128, 64, KP><<<dim3(BT_ / 128, NPC / 64), 256, 0, stream>>>(
      ob, Wprt, out, nullptr, x, b_proj, C_, C_, nullptr, nullptr);
  rmsnorm_bf16<<<BT_, 128, 0, stream>>>(out, g2, h1b);
  gemm_mfma<2, 128, 64, KP><<<dim3(BT_ / 128, C4 / 64), 256, 0, stream>>>(
      h1b, W1t, nullptr, ffb, nullptr, nullptr, C4, C4, nullptr, nullptr);
  gemm_mfma<3, 128, 64, C4><<<dim3(BT_ / 128, NPC / 64), 256, 0, stream>>>(
      ffb, W2t, out, nullptr, out, nullptr, C_, C_, nullptr, nullptr);
}